// Round 1
// baseline (37.817 us; speedup 1.0000x reference)
//
#include <hip/hip_runtime.h>

// Problem dims (fixed by reference setup_inputs)
constexpr int B = 4, P = 8, H = 32, W = 32, D = 32, C = 16;

__global__ __launch_bounds__(256) void resample3d_kernel(
    const float* __restrict__ fmap,   // [B,P,H,W,D,C]
    const float* __restrict__ theta,  // [B,P,3,4]
    float* __restrict__ out)          // [B,P,H,W,D,C]
{
    int idx = blockIdx.x * blockDim.x + threadIdx.x;   // [0, B*P*H*W*D*4)
    int c4  = idx & 3;          // which float4 chunk of the 16 channels
    int vox = idx >> 2;         // voxel id
    int k   = vox & (D - 1);            // D index
    int j   = (vox >> 5) & (W - 1);     // W index
    int i   = (vox >> 10) & (H - 1);    // H index
    int bp  = vox >> 15;                // b*P + p

    // theta row-major [3][4]: row0 -> y_s, row1 -> x_s, row2 -> z_s
    const float4* th4 = (const float4*)(theta + bp * 12);
    float4 t0 = th4[0];
    float4 t1 = th4[1];
    float4 t2 = th4[2];

    float fi = (float)i, fj = (float)j, fk = (float)k;
    // padded coords (reference adds +2 after the affine transform)
    float y = t0.x * fi + t0.y * fj + t0.z * fk + t0.w + 2.0f;
    float x = t1.x * fi + t1.y * fj + t1.z * fk + t1.w + 2.0f;
    float z = t2.x * fi + t2.y * fj + t2.z * fk + t2.w + 2.0f;

    // x0 = clip(floor(x), 0, H+2=34); xd = x - x0 (NOT re-clamped; matches ref)
    float fy0 = fminf(fmaxf(floorf(y), 0.0f), 34.0f);
    float fx0 = fminf(fmaxf(floorf(x), 0.0f), 34.0f);
    float fz0 = fminf(fmaxf(floorf(z), 0.0f), 34.0f);
    int y0 = (int)fy0, x0 = (int)fx0, z0 = (int)fz0;
    float yd = y - fy0, xd = x - fx0, zd = z - fz0;

    // base pointer for this (b,p) slice + channel-chunk
    const float* base = fmap + (size_t)bp * (H * W * D * C) + c4 * 4;

    float4 acc = make_float4(0.f, 0.f, 0.f, 0.f);

    #pragma unroll
    for (int dy = 0; dy < 2; ++dy) {
        float wy = dy ? yd : (1.0f - yd);
        int uy = y0 + dy - 2;                 // unpadded H index
        #pragma unroll
        for (int dx = 0; dx < 2; ++dx) {
            float wyx = wy * (dx ? xd : (1.0f - xd));
            int ux = x0 + dx - 2;             // unpadded W index
            #pragma unroll
            for (int dz = 0; dz < 2; ++dz) {
                float w = wyx * (dz ? zd : (1.0f - zd));
                int uz = z0 + dz - 2;         // unpadded D index
                if ((unsigned)uy < (unsigned)H &&
                    (unsigned)ux < (unsigned)W &&
                    (unsigned)uz < (unsigned)D) {
                    const float4 v =
                        *(const float4*)(base + ((size_t)((uy * W + ux) * D + uz) * C));
                    acc.x += w * v.x;
                    acc.y += w * v.y;
                    acc.z += w * v.z;
                    acc.w += w * v.w;
                }
            }
        }
    }

    *(float4*)(out + (size_t)vox * C + c4 * 4) = acc;
}

extern "C" void kernel_launch(void* const* d_in, const int* in_sizes, int n_in,
                              void* d_out, int out_size, void* d_ws, size_t ws_size,
                              hipStream_t stream) {
    const float* fmap  = (const float*)d_in[0];
    const float* theta = (const float*)d_in[1];
    float* out = (float*)d_out;

    const int total_threads = B * P * H * W * D * 4;   // 4 threads per voxel
    const int block = 256;
    const int grid = total_threads / block;            // 16384
    resample3d_kernel<<<grid, block, 0, stream>>>(fmap, theta, out);
}

// Round 2
// 29.144 us; speedup vs baseline: 1.2976x; 1.2976x over previous
//
#include <hip/hip_runtime.h>

// Problem dims (fixed by reference setup_inputs)
constexpr int B = 4, P = 8, H = 32, W = 32, D = 32, C = 16;

using f32x4 = __attribute__((ext_vector_type(4))) float;

__global__ __launch_bounds__(256) void resample3d_kernel(
    const float* __restrict__ fmap,   // [B,P,H,W,D,C]
    const float* __restrict__ theta,  // [B,P,3,4]
    float* __restrict__ out)          // [B,P,H,W,D,C]
{
    // 4 threads per voxel; block of 256 covers 64 consecutive voxels.
    // 32768 voxels per (b,p) => 512 blocks per (b,p): bp is block-uniform.
    const int bp  = blockIdx.x >> 9;
    const int tid = threadIdx.x;
    const int c4  = tid & 3;                        // float4 chunk of C=16
    const int vox = blockIdx.x * 64 + (tid >> 2);   // global voxel id
    const int k   =  vox        & (D - 1);
    const int j   = (vox >> 5)  & (W - 1);
    const int i   = (vox >> 10) & (H - 1);

    // theta row-major [3][4]; bp uniform -> compiler emits scalar loads
    const float4* th4 = (const float4*)(theta + bp * 12);
    const float4 t0 = th4[0];   // -> y_s
    const float4 t1 = th4[1];   // -> x_s
    const float4 t2 = th4[2];   // -> z_s

    const float fi = (float)i, fj = (float)j, fk = (float)k;
    // padded coords (reference adds +2 after the affine transform)
    const float y = fmaf(t0.x, fi, fmaf(t0.y, fj, fmaf(t0.z, fk, t0.w))) + 2.0f;
    const float x = fmaf(t1.x, fi, fmaf(t1.y, fj, fmaf(t1.z, fk, t1.w))) + 2.0f;
    const float z = fmaf(t2.x, fi, fmaf(t2.y, fj, fmaf(t2.z, fk, t2.w))) + 2.0f;

    // ref: x0 = clip(floor(x), 0, 34); xd = x - x0 (NOT re-clamped)
    const float fy0 = fminf(fmaxf(floorf(y), 0.0f), 34.0f);
    const float fx0 = fminf(fmaxf(floorf(x), 0.0f), 34.0f);
    const float fz0 = fminf(fmaxf(floorf(z), 0.0f), 34.0f);
    const float yd = y - fy0, xd = x - fx0, zd = z - fz0;

    // taps in UNPADDED coords: t?0 = ?0 - 2, t?1 = ?0 - 1.
    // OOB tap (pad region) contributes exactly 0 in the reference -> zero its
    // weight and clamp the address so the load is always safe (branchless).
    const int ty0 = (int)fy0 - 2, tx0 = (int)fx0 - 2, tz0 = (int)fz0 - 2;

    float wy[2], wx[2], wz[2];
    int   iy[2], ix[2], iz[2];
    wy[0] = ((unsigned)ty0       < (unsigned)H) ? (1.0f - yd) : 0.0f;
    wy[1] = ((unsigned)(ty0 + 1) < (unsigned)H) ? yd          : 0.0f;
    wx[0] = ((unsigned)tx0       < (unsigned)W) ? (1.0f - xd) : 0.0f;
    wx[1] = ((unsigned)(tx0 + 1) < (unsigned)W) ? xd          : 0.0f;
    wz[0] = ((unsigned)tz0       < (unsigned)D) ? (1.0f - zd) : 0.0f;
    wz[1] = ((unsigned)(tz0 + 1) < (unsigned)D) ? zd          : 0.0f;
    iy[0] = min(max(ty0, 0), H - 1);  iy[1] = min(max(ty0 + 1, 0), H - 1);
    ix[0] = min(max(tx0, 0), W - 1);  ix[1] = min(max(tx0 + 1, 0), W - 1);
    iz[0] = min(max(tz0, 0), D - 1);  iz[1] = min(max(tz0 + 1, 0), D - 1);

    const float* base = fmap + bp * (H * W * D * C) + c4 * 4;

    f32x4 acc = {0.f, 0.f, 0.f, 0.f};
    #pragma unroll
    for (int a = 0; a < 2; ++a) {
        const int offy = iy[a] * (W * D * C);
        #pragma unroll
        for (int b2 = 0; b2 < 2; ++b2) {
            const int offyx = offy + ix[b2] * (D * C);
            const float wyx = wy[a] * wx[b2];
            #pragma unroll
            for (int c2 = 0; c2 < 2; ++c2) {
                const float w = wyx * wz[c2];
                const f32x4 v = *(const f32x4*)(base + offyx + iz[c2] * C);
                acc += w * v;   // vector FMA per channel chunk
            }
        }
    }

    *(f32x4*)(out + vox * C + c4 * 4) = acc;
}

extern "C" void kernel_launch(void* const* d_in, const int* in_sizes, int n_in,
                              void* d_out, int out_size, void* d_ws, size_t ws_size,
                              hipStream_t stream) {
    const float* fmap  = (const float*)d_in[0];
    const float* theta = (const float*)d_in[1];
    float* out = (float*)d_out;

    const int total_threads = B * P * H * W * D * 4;   // 4 threads per voxel
    const int block = 256;
    const int grid = total_threads / block;            // 16384
    resample3d_kernel<<<grid, block, 0, stream>>>(fmap, theta, out);
}

// Round 3
// 28.381 us; speedup vs baseline: 1.3325x; 1.0269x over previous
//
#include <hip/hip_runtime.h>

// Problem dims (fixed by reference setup_inputs)
constexpr int B = 4, P = 8, H = 32, W = 32, D = 32, C = 16;

using f32x4 = __attribute__((ext_vector_type(4))) float;

__global__ __launch_bounds__(256) void resample3d_kernel(
    const float* __restrict__ fmap,   // [B,P,H,W,D,C]
    const float* __restrict__ theta,  // [B,P,3,4]
    float* __restrict__ out)          // [B,P,H,W,D,C]
{
    // 4 threads per voxel, 2 voxels per thread (vox and vox+64).
    // Block of 256 threads covers 128 consecutive voxels.
    // 32768 voxels per (b,p) => 256 blocks per (b,p): bp is block-uniform.
    const int bp  = blockIdx.x >> 8;
    const int tid = threadIdx.x;
    const int c4  = tid & 3;                         // float4 chunk of C=16
    const int vox0 = blockIdx.x * 128 + (tid >> 2);  // second voxel = vox0+64
    const int k   =  vox0        & (D - 1);
    const int j   = (vox0 >> 5)  & (W - 1);          // voxel1 has j+2 (no carry)
    const int i   = (vox0 >> 10) & (H - 1);

    // theta row-major [3][4]; bp block-uniform -> scalar loads
    const float4* th4 = (const float4*)(theta + bp * 12);
    const float4 t0 = th4[0];   // -> y_s
    const float4 t1 = th4[1];   // -> x_s
    const float4 t2 = th4[2];   // -> z_s

    const float fi = (float)i, fj = (float)j, fk = (float)k;
    float yv[2], xv[2], zv[2];
    yv[0] = fmaf(t0.x, fi, fmaf(t0.y, fj, fmaf(t0.z, fk, t0.w))) + 2.0f;
    xv[0] = fmaf(t1.x, fi, fmaf(t1.y, fj, fmaf(t1.z, fk, t1.w))) + 2.0f;
    zv[0] = fmaf(t2.x, fi, fmaf(t2.y, fj, fmaf(t2.z, fk, t2.w))) + 2.0f;
    yv[1] = yv[0] + 2.0f * t0.y;    // voxel1: j+2
    xv[1] = xv[0] + 2.0f * t1.y;
    zv[1] = zv[0] + 2.0f * t2.y;

    const float* base = fmap + bp * (H * W * D * C) + c4 * 4;

    // Per-voxel corner offsets and weights (branchless; pad taps get weight 0
    // and a clamped-safe address).
    int   off[2][8];
    float wgt[2][8];
    #pragma unroll
    for (int v = 0; v < 2; ++v) {
        const float y = yv[v], x = xv[v], z = zv[v];
        const float fy0 = fminf(fmaxf(floorf(y), 0.0f), 34.0f);
        const float fx0 = fminf(fmaxf(floorf(x), 0.0f), 34.0f);
        const float fz0 = fminf(fmaxf(floorf(z), 0.0f), 34.0f);
        const float yd = y - fy0, xd = x - fx0, zd = z - fz0;
        const int ty0 = (int)fy0 - 2, tx0 = (int)fx0 - 2, tz0 = (int)fz0 - 2;

        float wy[2], wx[2], wz[2];
        int   iy[2], ix[2], iz[2];
        wy[0] = ((unsigned)ty0       < (unsigned)H) ? (1.0f - yd) : 0.0f;
        wy[1] = ((unsigned)(ty0 + 1) < (unsigned)H) ? yd          : 0.0f;
        wx[0] = ((unsigned)tx0       < (unsigned)W) ? (1.0f - xd) : 0.0f;
        wx[1] = ((unsigned)(tx0 + 1) < (unsigned)W) ? xd          : 0.0f;
        wz[0] = ((unsigned)tz0       < (unsigned)D) ? (1.0f - zd) : 0.0f;
        wz[1] = ((unsigned)(tz0 + 1) < (unsigned)D) ? zd          : 0.0f;
        iy[0] = min(max(ty0, 0), H - 1);  iy[1] = min(max(ty0 + 1, 0), H - 1);
        ix[0] = min(max(tx0, 0), W - 1);  ix[1] = min(max(tx0 + 1, 0), W - 1);
        iz[0] = min(max(tz0, 0), D - 1);  iz[1] = min(max(tz0 + 1, 0), D - 1);

        #pragma unroll
        for (int a = 0; a < 2; ++a)
            #pragma unroll
            for (int b2 = 0; b2 < 2; ++b2)
                #pragma unroll
                for (int c2 = 0; c2 < 2; ++c2) {
                    const int cn = a * 4 + b2 * 2 + c2;
                    off[v][cn] = (iy[a] * (W * D) + ix[b2] * D + iz[c2]) * C;
                    wgt[v][cn] = wy[a] * wx[b2] * wz[c2];
                }
    }

    // Issue all 16 loads (compiler hoists into one vmcnt group), then blend.
    f32x4 val[2][8];
    #pragma unroll
    for (int cn = 0; cn < 8; ++cn) {
        val[0][cn] = *(const f32x4*)(base + off[0][cn]);
        val[1][cn] = *(const f32x4*)(base + off[1][cn]);
    }

    f32x4 acc0 = {0.f, 0.f, 0.f, 0.f};
    f32x4 acc1 = {0.f, 0.f, 0.f, 0.f};
    #pragma unroll
    for (int cn = 0; cn < 8; ++cn) {
        acc0 += wgt[0][cn] * val[0][cn];
        acc1 += wgt[1][cn] * val[1][cn];
    }

    // Output is write-once: bypass caches so fmap stays resident.
    float* outp = out + (size_t)vox0 * C + c4 * 4;
    __builtin_nontemporal_store(acc0, (f32x4*)outp);
    __builtin_nontemporal_store(acc1, (f32x4*)(outp + 64 * C));
}

extern "C" void kernel_launch(void* const* d_in, const int* in_sizes, int n_in,
                              void* d_out, int out_size, void* d_ws, size_t ws_size,
                              hipStream_t stream) {
    const float* fmap  = (const float*)d_in[0];
    const float* theta = (const float*)d_in[1];
    float* out = (float*)d_out;

    const int total_threads = B * P * H * W * D * 4 / 2;  // 4/voxel, 2 voxels/thread
    const int block = 256;
    const int grid = total_threads / block;               // 8192
    resample3d_kernel<<<grid, block, 0, stream>>>(fmap, theta, out);
}